// Round 2
// baseline (168.353 us; speedup 1.0000x reference)
//
#include <hip/hip_runtime.h>
#include <hip/hip_bf16.h>

// ---------------------------------------------------------------------------
// SAGAN-style spatial self-attention, B=4 C=128 H=W=64 (N=4096), CQK=16.
//   q = Wq x + bq ; k = Wk x + bk ; v = Wv x + bv   (1x1 convs)
//   S[b,i,j] = sum_d q[d,i] k[d,j] ; P = softmax_j(S) ; O[c,i] = sum_j v[c,j] P[i,j]
//   out = gamma*O + x
// Plan: proj (MFMA) -> flash attention (MFMA 32x32x16 bf16, swapped QK^T,
// per-lane online softmax, KV-split JS for occupancy) -> merge (+gamma,x).
// ---------------------------------------------------------------------------

#define BN 4
#define CC 128
#define NN 4096
#define DQK 16

typedef float f32x16 __attribute__((ext_vector_type(16)));
typedef short s16x8 __attribute__((ext_vector_type(8)));
typedef unsigned short u16;

union FragU { unsigned u[4]; s16x8 v; };

// round-to-nearest-even bf16 from f32 bits (finite inputs only)
__device__ inline u16 bf16_bits(float f) {
  unsigned u = __builtin_bit_cast(unsigned, f);
  unsigned r = u + 0x7fffu + ((u >> 16) & 1u);
  return (u16)(r >> 16);
}
__device__ inline unsigned pack_bf16(float lo, float hi) {
  return ((unsigned)bf16_bits(hi) << 16) | (unsigned)bf16_bits(lo);
}
__device__ inline u16 to_bf16(float f) { return bf16_bits(f); }

// ---------------------------------------------------------------------------
// Kernel 1: fused QKV projection.
// grid = B*128 blocks (1 wave each); block handles (b, 32 n-positions).
// Writes Qt[b][n][16] (bf16, pre-scaled by log2e), Kt[b][n][16], Vb[b][c][n].
// ---------------------------------------------------------------------------
__global__ __launch_bounds__(64) void proj_kernel(
    const float* __restrict__ x,
    const float* __restrict__ Wq, const float* __restrict__ bq,
    const float* __restrict__ Wk, const float* __restrict__ bk,
    const float* __restrict__ Wv, const float* __restrict__ bv,
    u16* __restrict__ Qt, u16* __restrict__ Kt, u16* __restrict__ Vb)
{
  __shared__ float xs[CC * 32];          // [c][nn], 16 KiB
  const int lane = threadIdx.x;
  const int l31 = lane & 31, h = lane >> 5;
  const int bid = blockIdx.x;
  const int b = bid >> 7;
  const int n0 = (bid & 127) * 32;

  const float* xb = x + ((size_t)b * CC) * NN + n0;
  // stage x tile: 4096 floats = 1024 float4, coalesced
  #pragma unroll
  for (int k = 0; k < 16; ++k) {
    int idx4 = lane + 64 * k;            // 0..1023
    int c = idx4 >> 3;
    int nn4 = (idx4 & 7) * 4;
    float4 vv = *reinterpret_cast<const float4*>(xb + (size_t)c * NN + nn4);
    *reinterpret_cast<float4*>(&xs[c * 32 + nn4]) = vv;
  }
  __syncthreads();

  // B-operand frags from x: B[k=c][n], lane holds col n=l31, k = 16*ks+8*h+e
  s16x8 bx[8];
  #pragma unroll
  for (int ks = 0; ks < 8; ++ks) {
    FragU f;
    #pragma unroll
    for (int q = 0; q < 4; ++q) {
      int c = 16 * ks + 8 * h + 2 * q;
      f.u[q] = pack_bf16(xs[c * 32 + l31], xs[(c + 1) * 32 + l31]);
    }
    bx[ks] = f.v;
  }

  f32x16 zero;
  #pragma unroll
  for (int r = 0; r < 16; ++r) zero[r] = 0.f;

  const float LOG2E = 1.44269504088896340736f;

  // ---- Q+K stacked as one 32-row A tile ----
  {
    const float* wrow = (l31 < 16) ? (Wq + (size_t)l31 * CC)
                                   : (Wk + (size_t)(l31 - 16) * CC);
    f32x16 acc = zero;
    #pragma unroll
    for (int ks = 0; ks < 8; ++ks) {
      const float* wp = wrow + 16 * ks + 8 * h;
      float4 w0 = *reinterpret_cast<const float4*>(wp);
      float4 w1 = *reinterpret_cast<const float4*>(wp + 4);
      FragU a;
      a.u[0] = pack_bf16(w0.x, w0.y); a.u[1] = pack_bf16(w0.z, w0.w);
      a.u[2] = pack_bf16(w1.x, w1.y); a.u[3] = pack_bf16(w1.z, w1.w);
      acc = __builtin_amdgcn_mfma_f32_32x32x16_bf16(a.v, bx[ks], acc, 0, 0, 0);
    }
    #pragma unroll
    for (int r = 0; r < 16; ++r) {
      int row = (r & 3) + 8 * (r >> 2) + 4 * h;   // 0..31
      float val = acc[r];
      if (row < 16) {
        val = (val + bq[row]) * LOG2E;            // fold exp2 scaling into q
        Qt[((size_t)b * NN + n0 + l31) * DQK + row] = to_bf16(val);
      } else {
        val += bk[row - 16];
        Kt[((size_t)b * NN + n0 + l31) * DQK + (row - 16)] = to_bf16(val);
      }
    }
  }

  // ---- V: 4 row tiles of 32 ----
  #pragma unroll
  for (int rt = 0; rt < 4; ++rt) {
    const float* vrow = Wv + (size_t)(rt * 32 + l31) * CC;
    f32x16 acc = zero;
    #pragma unroll
    for (int ks = 0; ks < 8; ++ks) {
      const float* wp = vrow + 16 * ks + 8 * h;
      float4 w0 = *reinterpret_cast<const float4*>(wp);
      float4 w1 = *reinterpret_cast<const float4*>(wp + 4);
      FragU a;
      a.u[0] = pack_bf16(w0.x, w0.y); a.u[1] = pack_bf16(w0.z, w0.w);
      a.u[2] = pack_bf16(w1.x, w1.y); a.u[3] = pack_bf16(w1.z, w1.w);
      acc = __builtin_amdgcn_mfma_f32_32x32x16_bf16(a.v, bx[ks], acc, 0, 0, 0);
    }
    #pragma unroll
    for (int r = 0; r < 16; ++r) {
      int e = rt * 32 + (r & 3) + 8 * (r >> 2) + 4 * h;
      Vb[((size_t)b * CC + e) * NN + n0 + l31] = to_bf16(acc[r] + bv[e]);
    }
  }
}

// ---------------------------------------------------------------------------
// Kernel 2: flash attention, 1 wave per (b, 32-row q-tile, kv-segment).
// Swapped QK^T: S^T = mfma(K, Q) so each lane owns one q-row (col = lane&31).
// O^T accumulated (cols lane-mapped by i) so online-softmax rescale is
// purely per-lane. Partial (O, m, l) written per segment; merged later.
// ---------------------------------------------------------------------------
__global__ __launch_bounds__(64, 2) void flash_kernel(
    const u16* __restrict__ Qt, const u16* __restrict__ Kt,
    const u16* __restrict__ Vb,
    float* __restrict__ Opart, float* __restrict__ mstat,
    float* __restrict__ lstat, int JS)
{
  const int lane = threadIdx.x;
  const int l31 = lane & 31, h = lane >> 5;
  const int bid = blockIdx.x;               // ((b*JS + sg)*128) + it
  const int it = bid & 127;
  const int bs = bid >> 7;
  const int b = bs / JS;
  const int sg = bs % JS;
  const int i0 = it * 32;
  const int seglen = NN / JS;
  const int j_begin = sg * seglen;
  const int ntiles = seglen / 32;

  f32x16 zero;
  #pragma unroll
  for (int r = 0; r < 16; ++r) zero[r] = 0.f;

  // Q A/B frag: lane holds Q'[i0+l31][8h+e]
  s16x8 qf = *reinterpret_cast<const s16x8*>(
      Qt + ((size_t)b * NN + i0 + l31) * DQK + 8 * h);

  const u16* Kb = Kt + (size_t)b * NN * DQK;
  const u16* Vbb = Vb + (size_t)b * CC * NN;

  f32x16 acc[4];
  #pragma unroll
  for (int ct = 0; ct < 4; ++ct) acc[ct] = zero;
  float m_run = -__builtin_inff();
  float l_run = 0.f;

  for (int t = 0; t < ntiles; ++t) {
    const int j0 = j_begin + t * 32;
    // K frag (A-operand of S^T): K'[j0+l31][8h+e]
    s16x8 kf = *reinterpret_cast<const s16x8*>(
        Kb + (size_t)(j0 + l31) * DQK + 8 * h);
    // V frags (A-operand of PV): v[32ct+l31][j0+16ks+8h+e] — issue early
    s16x8 vf[8];
    #pragma unroll
    for (int ct = 0; ct < 4; ++ct)
      #pragma unroll
      for (int ks = 0; ks < 2; ++ks)
        vf[ct * 2 + ks] = *reinterpret_cast<const s16x8*>(
            Vbb + (size_t)(ct * 32 + l31) * NN + j0 + 16 * ks + 8 * h);

    // S^T[j,i]: col i = l31 (lane-local q-row), rows j over regs
    f32x16 sv = __builtin_amdgcn_mfma_f32_32x32x16_bf16(kf, qf, zero, 0, 0, 0);

    // ---- online softmax (log2-domain; Q pre-scaled by log2e) ----
    float tmax = sv[0];
    #pragma unroll
    for (int r = 1; r < 16; ++r) tmax = fmaxf(tmax, sv[r]);
    float cmb = fmaxf(tmax, __shfl_xor(tmax, 32));
    float m_new = (cmb > m_run + 8.f) ? cmb : m_run;   // defer-max (T13)
    if (__any(m_new > m_run)) {
      float alpha = __builtin_amdgcn_exp2f(m_run - m_new);
      l_run *= alpha;
      #pragma unroll
      for (int ct = 0; ct < 4; ++ct)
        #pragma unroll
        for (int r = 0; r < 16; ++r) acc[ct][r] *= alpha;
    }
    m_run = m_new;

    float p[16];
    float ps = 0.f;
    #pragma unroll
    for (int r = 0; r < 16; ++r) {
      p[r] = __builtin_amdgcn_exp2f(sv[r] - m_run);
      ps += p[r];
    }
    l_run += ps;

    // pack P to bf16 pairs; exchange halves so each lane holds contiguous-j
    // B-operand frags. jofs(r,h) = (r&3)+8*(r>>2)+4h.
    unsigned w[8], xw[8];
    #pragma unroll
    for (int q = 0; q < 8; ++q) w[q] = pack_bf16(p[2 * q], p[2 * q + 1]);
    #pragma unroll
    for (int q = 0; q < 8; ++q)
      xw[q] = (unsigned)__shfl_xor((int)w[q], 32);
    FragU f0, f1;
    f0.u[0] = h ? xw[2] : w[0];
    f0.u[1] = h ? xw[3] : w[1];
    f0.u[2] = h ? w[2] : xw[0];
    f0.u[3] = h ? w[3] : xw[1];
    f1.u[0] = h ? xw[6] : w[4];
    f1.u[1] = h ? xw[7] : w[5];
    f1.u[2] = h ? w[6] : xw[4];
    f1.u[3] = h ? w[7] : xw[5];

    // PV: O^T[c,i] += sum_j v[c,j] P[i,j]
    #pragma unroll
    for (int ct = 0; ct < 4; ++ct) {
      acc[ct] = __builtin_amdgcn_mfma_f32_32x32x16_bf16(vf[ct * 2 + 0], f0.v,
                                                        acc[ct], 0, 0, 0);
      acc[ct] = __builtin_amdgcn_mfma_f32_32x32x16_bf16(vf[ct * 2 + 1], f1.v,
                                                        acc[ct], 0, 0, 0);
    }
  }

  float l_tot = l_run + __shfl_xor(l_run, 32);

  float* Ob = Opart + ((size_t)(b * JS + sg) * CC) * NN;
  #pragma unroll
  for (int ct = 0; ct < 4; ++ct)
    #pragma unroll
    for (int r = 0; r < 16; ++r) {
      int c = 32 * ct + (r & 3) + 8 * (r >> 2) + 4 * h;
      Ob[(size_t)c * NN + i0 + l31] = acc[ct][r];
    }
  if (lane < 32) {
    mstat[((size_t)(b * JS + sg)) * NN + i0 + l31] = m_run;
    lstat[((size_t)(b * JS + sg)) * NN + i0 + l31] = l_tot;
  }
}

// ---------------------------------------------------------------------------
// Kernel 3: merge KV-split partials, normalize, out = gamma*O + x.
// grid = B*N/64 blocks x 256 threads. Coalesced over i.
// ---------------------------------------------------------------------------
template <int JS>
__global__ __launch_bounds__(256) void merge_kernel(
    const float* __restrict__ Opart, const float* __restrict__ mstat,
    const float* __restrict__ lstat, const float* __restrict__ x,
    const float* __restrict__ gamma, float* __restrict__ out)
{
  const int t = threadIdx.x;
  const int ii = t & 63, cg = t >> 6;
  const int bid = blockIdx.x;
  const int b = bid >> 6;
  const int i = ((bid & 63) << 6) + ii;

  float ms[JS], wgt[JS];
  float m = -__builtin_inff();
  #pragma unroll
  for (int s = 0; s < JS; ++s) {
    ms[s] = mstat[((size_t)(b * JS + s)) * NN + i];
    m = fmaxf(m, ms[s]);
  }
  float denom = 0.f;
  #pragma unroll
  for (int s = 0; s < JS; ++s) {
    wgt[s] = __builtin_amdgcn_exp2f(ms[s] - m);
    denom += wgt[s] * lstat[((size_t)(b * JS + s)) * NN + i];
  }
  const float g = gamma[0] / denom;
  #pragma unroll
  for (int s = 0; s < JS; ++s) wgt[s] *= g;

  #pragma unroll 4
  for (int cc = 0; cc < 32; ++cc) {
    int c = cg * 32 + cc;
    float o = 0.f;
    #pragma unroll
    for (int s = 0; s < JS; ++s)
      o += wgt[s] * Opart[((size_t)(b * JS + s) * CC + c) * NN + i];
    size_t oidx = ((size_t)b * CC + c) * NN + i;
    out[oidx] = o + x[oidx];
  }
}

// ---------------------------------------------------------------------------
extern "C" void kernel_launch(void* const* d_in, const int* in_sizes, int n_in,
                              void* d_out, int out_size, void* d_ws,
                              size_t ws_size, hipStream_t stream)
{
  const float* x     = (const float*)d_in[0];
  const float* Wq    = (const float*)d_in[1];
  const float* bq    = (const float*)d_in[2];
  const float* Wk    = (const float*)d_in[3];
  const float* bk    = (const float*)d_in[4];
  const float* Wv    = (const float*)d_in[5];
  const float* bv    = (const float*)d_in[6];
  const float* gamma = (const float*)d_in[7];
  float* out = (float*)d_out;

  char* wsb = (char*)d_ws;
  const size_t szQ = (size_t)BN * NN * DQK * 2;        // 512 KiB
  const size_t szV = (size_t)BN * CC * NN * 2;         // 4 MiB
  const size_t base = 2 * szQ + szV;
  auto need = [&](size_t js) {
    return base + js * ((size_t)2 * BN * NN * 4 + (size_t)BN * CC * NN * 4);
  };
  int JS = 4;
  if (ws_size < need(4)) JS = 2;
  if (ws_size < need(2)) JS = 1;

  u16* Qt = (u16*)(wsb);
  u16* Kt = (u16*)(wsb + szQ);
  u16* Vb = (u16*)(wsb + 2 * szQ);
  float* mstat = (float*)(wsb + base);
  float* lstat = (float*)(wsb + base + (size_t)JS * BN * NN * 4);
  float* Opart = (float*)(wsb + base + (size_t)2 * JS * BN * NN * 4);

  proj_kernel<<<dim3(BN * 128), dim3(64), 0, stream>>>(
      x, Wq, bq, Wk, bk, Wv, bv, Qt, Kt, Vb);
  flash_kernel<<<dim3(BN * 128 * JS), dim3(64), 0, stream>>>(
      Qt, Kt, Vb, Opart, mstat, lstat, JS);
  if (JS == 4)
    merge_kernel<4><<<dim3(BN * 64), dim3(256), 0, stream>>>(
        Opart, mstat, lstat, x, gamma, out);
  else if (JS == 2)
    merge_kernel<2><<<dim3(BN * 64), dim3(256), 0, stream>>>(
        Opart, mstat, lstat, x, gamma, out);
  else
    merge_kernel<1><<<dim3(BN * 64), dim3(256), 0, stream>>>(
        Opart, mstat, lstat, x, gamma, out);
}